// Round 5
// baseline (734.165 us; speedup 1.0000x reference)
//
#include <hip/hip_runtime.h>
#include <stdint.h>

#define NN    6000
#define KNNC  10
#define MM    (NN * 2 * (KNNC + 1))   // 132000
#define DD    (2 * NN)                // 12000
#define LCH   3                       // hidden layers (LC-1)
#define BLK   256

// One MLP wave (64 rows) per block -> ceil(132000/64) = 2063 blocks.
#define FBLOCKS ((MM + 63) / 64)      // 2063
#define NV      ((long long)DD * DD / 4)   // 36,000,000 float4s

// Native clang vector type: __builtin_nontemporal_store rejects HIP's
// class-based float4, but accepts ext_vector_type.
typedef float v4f __attribute__((ext_vector_type(4)));

// Wave-specialized fused kernel: per block of 4 waves, 3 waves stream
// float4 zeros into the 576MB output (nontemporal), 1 wave computes 64 MLP
// rows (one per lane) with wave-uniform weight reads (-> s_load broadcast).
// Fill and MLP waves are co-resident on every CU, so the VALU work of the
// MLP (~21us aggregate) hides under the ~93us HBM store drain.
// The MLP wave slot rotates with blockIdx so MLP waves spread across SIMDs.
__global__ __launch_bounds__(BLK) void fused_mlp_zero(
    const float* __restrict__ CK,    // [MM,3]
    const float* __restrict__ Win,   // [3,64]
    const float* __restrict__ bin,   // [64]
    const float* __restrict__ Whid,  // [3,64,64]
    const float* __restrict__ bhid,  // [3,64]
    const float* __restrict__ Wout,  // [64,4]
    const float* __restrict__ bout,  // [4]
    float* __restrict__ vals,        // [MM,2] (workspace)
    float* __restrict__ out)         // [DD*DD], zero-filled here
{
    const int tid  = threadIdx.x;
    const int wave = tid >> 6;
    const int lane = tid & 63;
    const int mlpw = blockIdx.x & 3;          // which wave does MLP (rotates)

    if (wave != mlpw) {
        // ---- fill specialization: 3 waves per block ----
        const int fw = wave - (wave > mlpw ? 1 : 0);       // 0..2
        const long long ft = (long long)blockIdx.x * 192 + fw * 64 + lane;
        const long long stride = (long long)FBLOCKS * 192;
        v4f z = (v4f){0.f, 0.f, 0.f, 0.f};
        v4f* outv = (v4f*)out;
        for (long long i = ft; i < NV; i += stride)
            __builtin_nontemporal_store(z, outv + i);
        return;
    }

    // ---- MLP specialization: one row per lane ----
    const int m = blockIdx.x * 64 + lane;
    if (m >= MM) return;

    const float x0 = CK[m * 3 + 0];
    const float x1 = CK[m * 3 + 1];
    const float x2 = CK[m * 3 + 2];

    // Input layer 3 -> 64; weight/bias indices wave-uniform -> SGPR broadcast.
    float h[64];
#pragma unroll
    for (int j = 0; j < 64; j++) {
        float a = bin[j];
        a = fmaf(x0, Win[j],       a);
        a = fmaf(x1, Win[64 + j],  a);
        a = fmaf(x2, Win[128 + j], a);
        h[j] = fmaxf(a, 0.0f);
    }

    // Hidden layers: g_j = sum_k W[k][j] * h_k (row-major W matches h @ W).
#pragma unroll 1
    for (int l = 0; l < LCH; l++) {
        const float* __restrict__ W  = Whid + (l << 12);
        const float* __restrict__ bh = bhid + (l << 6);
        float g[64];
#pragma unroll
        for (int j = 0; j < 64; j++) g[j] = bh[j];
#pragma unroll 1
        for (int k = 0; k < 64; k++) {       // unroll 1: keep body = 64 FMA, no I$ bloat
            const float hk = h[k];
            const float* __restrict__ Wk = W + (k << 6);
#pragma unroll
            for (int j = 0; j < 64; j++) g[j] = fmaf(Wk[j], hk, g[j]);
        }
#pragma unroll
        for (int j = 0; j < 64; j++) h[j] = fmaxf(g[j], 0.0f);
    }

    // Output layer collapsed over mi: vals[:,mj] = C[:,mj] + C[:,mj+2]
    float v0 = bout[0] + bout[2];
    float v1 = bout[1] + bout[3];
#pragma unroll
    for (int k = 0; k < 64; k++) {
        v0 = fmaf(h[k], Wout[k * 4 + 0] + Wout[k * 4 + 2], v0);
        v1 = fmaf(h[k], Wout[k * 4 + 1] + Wout[k * 4 + 3], v1);
    }
    vals[m * 2 + 0] = v0;
    vals[m * 2 + 1] = v1;
}

__global__ __launch_bounds__(BLK) void scatter_add(
    const float* __restrict__ vals,   // [MM,2]
    const int* __restrict__ coo,      // [2,MM]
    float* __restrict__ out)          // [DD*DD]
{
    const int t = blockIdx.x * BLK + threadIdx.x;
    if (t >= MM) return;
    const int r2 = coo[t] * 2;        // row index * MODES
    const int c2 = coo[MM + t] * 2;   // col index * MODES
    const float v0 = vals[t * 2 + 0];
    const float v1 = vals[t * 2 + 1];
    // mj=0: element (r2, c2); mj=1: element (r2+1, c2+1) = +DD+1 flat
    const long long f0 = (long long)r2 * DD + c2;
    atomicAdd(out + f0, v0);
    atomicAdd(out + f0 + DD + 1, v1);
}

extern "C" void kernel_launch(void* const* d_in, const int* in_sizes, int n_in,
                              void* d_out, int out_size, void* d_ws, size_t ws_size,
                              hipStream_t stream) {
    const float* CK   = (const float*)d_in[0];
    const float* Win  = (const float*)d_in[1];
    const float* bin  = (const float*)d_in[2];
    const float* Whid = (const float*)d_in[3];
    const float* bhid = (const float*)d_in[4];
    const float* Wout = (const float*)d_in[5];
    const float* bout = (const float*)d_in[6];
    const int* coo    = (const int*)d_in[7];
    float* out        = (float*)d_out;
    float* vals       = (float*)d_ws;

    fused_mlp_zero<<<FBLOCKS, BLK, 0, stream>>>(
        CK, Win, bin, Whid, bhid, Wout, bout, vals, out);
    scatter_add<<<(MM + BLK - 1) / BLK, BLK, 0, stream>>>(vals, coo, out);
}

// Round 6
// 710.751 us; speedup vs baseline: 1.0329x; 1.0329x over previous
//
#include <hip/hip_runtime.h>
#include <stdint.h>

#define NN    6000
#define KNNC  10
#define MM    (NN * 2 * (KNNC + 1))   // 132000
#define DD    (2 * NN)                // 12000
#define LCH   3                       // hidden layers (LC-1)
#define BLK   256

// One MLP wave (64 rows) per block -> ceil(132000/64) = 2063 blocks.
#define FBLOCKS ((MM + 63) / 64)      // 2063
#define NV      ((long long)DD * DD / 4)   // 36,000,000 float4s

// Wave-specialized fused kernel: per block of 4 waves, 3 waves stream float4
// zeros into the 576MB output (plain stores - proven 6.1 TB/s by the harness
// fill), 1 wave computes 64 MLP rows (one per lane) with wave-uniform float4
// weight loads. Fill and MLP waves are co-resident on every CU, so the ~21us
// aggregate MLP VALU work hides under the ~93us HBM store drain.
// k-loop unrolled x8 so weight loads batch and pipeline ahead of the FMAs
// (round-5 post-mortem: unroll(1) forced load->wait->use serialization, ~7x
// VALU stall). Layer loop stays rolled: one ~5KB body, not 3, fits I$.
__global__ __launch_bounds__(BLK) void fused_mlp_zero(
    const float* __restrict__ CK,    // [MM,3]
    const float* __restrict__ Win,   // [3,64]
    const float* __restrict__ bin,   // [64]
    const float* __restrict__ Whid,  // [3,64,64]
    const float* __restrict__ bhid,  // [3,64]
    const float* __restrict__ Wout,  // [64,4]
    const float* __restrict__ bout,  // [4]
    float* __restrict__ vals,        // [MM,2] (workspace)
    float* __restrict__ out)         // [DD*DD], zero-filled here
{
    const int tid  = threadIdx.x;
    const int wave = tid >> 6;
    const int lane = tid & 63;
    const int mlpw = blockIdx.x & 3;          // rotate MLP wave slot across SIMDs

    if (wave != mlpw) {
        // ---- fill specialization: 3 waves per block ----
        const int fw = wave - (wave > mlpw ? 1 : 0);       // 0..2
        const long long ft = (long long)blockIdx.x * 192 + fw * 64 + lane;
        const long long stride = (long long)FBLOCKS * 192;
        float4 z = make_float4(0.f, 0.f, 0.f, 0.f);
        float4* outv = (float4*)out;
        for (long long i = ft; i < NV; i += stride) outv[i] = z;
        return;
    }

    // ---- MLP specialization: one row per lane ----
    const int m = blockIdx.x * 64 + lane;
    if (m >= MM) return;

    const float x0 = CK[m * 3 + 0];
    const float x1 = CK[m * 3 + 1];
    const float x2 = CK[m * 3 + 2];

    // Input layer 3 -> 64; weight/bias reads wave-uniform (broadcast).
    float h[64];
#pragma unroll
    for (int j = 0; j < 64; j++) {
        float a = bin[j];
        a = fmaf(x0, Win[j],       a);
        a = fmaf(x1, Win[64 + j],  a);
        a = fmaf(x2, Win[128 + j], a);
        h[j] = fmaxf(a, 0.0f);
    }

    // Hidden layers: g_j = sum_k W[k][j] * h_k (row-major W matches h @ W).
#pragma unroll 1
    for (int l = 0; l < LCH; l++) {
        const float4* __restrict__ W4 = (const float4*)(Whid + (l << 12));
        const float*  __restrict__ bh = bhid + (l << 6);
        float g[64];
#pragma unroll
        for (int j = 0; j < 64; j++) g[j] = bh[j];
#pragma unroll 8
        for (int k = 0; k < 64; k++) {
            const float hk = h[k];
            const float4* __restrict__ Wk = W4 + (k << 4);   // row k: 16 float4s
#pragma unroll
            for (int j4 = 0; j4 < 16; j4++) {
                float4 w = Wk[j4];
                g[j4 * 4 + 0] = fmaf(w.x, hk, g[j4 * 4 + 0]);
                g[j4 * 4 + 1] = fmaf(w.y, hk, g[j4 * 4 + 1]);
                g[j4 * 4 + 2] = fmaf(w.z, hk, g[j4 * 4 + 2]);
                g[j4 * 4 + 3] = fmaf(w.w, hk, g[j4 * 4 + 3]);
            }
        }
#pragma unroll
        for (int j = 0; j < 64; j++) h[j] = fmaxf(g[j], 0.0f);
    }

    // Output layer collapsed over mi: vals[:,mj] = C[:,mj] + C[:,mj+2]
    float v0 = bout[0] + bout[2];
    float v1 = bout[1] + bout[3];
#pragma unroll
    for (int k = 0; k < 64; k++) {
        float4 wo = *((const float4*)Wout + k);
        v0 = fmaf(h[k], wo.x + wo.z, v0);
        v1 = fmaf(h[k], wo.y + wo.w, v1);
    }
    vals[m * 2 + 0] = v0;
    vals[m * 2 + 1] = v1;
}

__global__ __launch_bounds__(BLK) void scatter_add(
    const float* __restrict__ vals,   // [MM,2]
    const int* __restrict__ coo,      // [2,MM]
    float* __restrict__ out)          // [DD*DD]
{
    const int t = blockIdx.x * BLK + threadIdx.x;
    if (t >= MM) return;
    const int r2 = coo[t] * 2;        // row index * MODES
    const int c2 = coo[MM + t] * 2;   // col index * MODES
    const float v0 = vals[t * 2 + 0];
    const float v1 = vals[t * 2 + 1];
    // mj=0: element (r2, c2); mj=1: element (r2+1, c2+1) = +DD+1 flat
    const long long f0 = (long long)r2 * DD + c2;
    atomicAdd(out + f0, v0);
    atomicAdd(out + f0 + DD + 1, v1);
}

extern "C" void kernel_launch(void* const* d_in, const int* in_sizes, int n_in,
                              void* d_out, int out_size, void* d_ws, size_t ws_size,
                              hipStream_t stream) {
    const float* CK   = (const float*)d_in[0];
    const float* Win  = (const float*)d_in[1];
    const float* bin  = (const float*)d_in[2];
    const float* Whid = (const float*)d_in[3];
    const float* bhid = (const float*)d_in[4];
    const float* Wout = (const float*)d_in[5];
    const float* bout = (const float*)d_in[6];
    const int* coo    = (const int*)d_in[7];
    float* out        = (float*)d_out;
    float* vals       = (float*)d_ws;

    fused_mlp_zero<<<FBLOCKS, BLK, 0, stream>>>(
        CK, Win, bin, Whid, bhid, Wout, bout, vals, out);
    scatter_add<<<(MM + BLK - 1) / BLK, BLK, 0, stream>>>(vals, coo, out);
}